// Round 3
// baseline (468.301 us; speedup 1.0000x reference)
//
#include <hip/hip_runtime.h>

// ---------------------------------------------------------------------------
// MultiHeadAttention: B=4 S=2048 MODEL=1024 H=16 Dk=Dv=64, causal.
// cast(QKV->bf16) ; LDS-tiled weight transpose (Wq pre-scaled 1/8) ;
// 3x proj GEMM (dbuf, bf16 MFMA) -> q,k,vT ; flash causal attn (1 strip/block,
// XCD-chunked KV locality, ones-MFMA row-sum) ; out GEMM (dbuf, +bias, f32).
// Mask input is statically causal -> arithmetic.
// LDS tiles: 128B rows, XOR swizzle byte^=((row&7)<<4), global_load_lds(16B)
// from pre-swizzled global addresses (rule #21).
// ---------------------------------------------------------------------------

typedef __bf16 bf16;
typedef __attribute__((ext_vector_type(8))) __bf16 bf16x8;
typedef __attribute__((ext_vector_type(4))) __bf16 bf16x4;
typedef __attribute__((ext_vector_type(4))) float f32x4;
typedef unsigned int u32;

#define GLB_AS __attribute__((address_space(1)))
#define LDS_AS __attribute__((address_space(3)))

#define L2E 1.44269504088896340736f

static __device__ __forceinline__ void stage_swz(const bf16* __restrict__ g, long ldelem,
                                                 long row0, long col0,
                                                 bf16* lds, int rows, int tid)
{
    const int lane = tid & 63;
    const int wave = tid >> 6;
    const int nch = rows >> 3;                       // 1KB chunks
    for (int c = wave; c < nch; c += 4) {
        unsigned o  = ((unsigned)c << 10) + ((unsigned)lane << 4); // linear byte in tile
        unsigned r  = o >> 7;                         // tile row (128B/row)
        unsigned cb = o & 127u;                       // byte within row
        unsigned cs = cb ^ ((r & 7u) << 4);           // pre-swizzled source byte
        const bf16* src = g + (row0 + (long)r) * ldelem + col0 + (long)(cs >> 1);
        char* dst = (char*)lds + ((unsigned)c << 10); // wave-uniform, linear
        __builtin_amdgcn_global_load_lds((GLB_AS u32*)src, (LDS_AS u32*)dst, 16, 0, 0);
    }
}

// ---------------------------------------------------------------------------
// Prep kernels
// ---------------------------------------------------------------------------
__global__ void cast3(const float4* __restrict__ a, const float4* __restrict__ b,
                      const float4* __restrict__ c,
                      bf16x4* __restrict__ xa, bf16x4* __restrict__ xb,
                      bf16x4* __restrict__ xc)
{
    const int n4 = (8192 * 1024) / 4;
    for (int i = blockIdx.x * blockDim.x + threadIdx.x; i < n4; i += gridDim.x * blockDim.x) {
        float4 v;
        v = a[i]; xa[i] = (bf16x4){(bf16)v.x, (bf16)v.y, (bf16)v.z, (bf16)v.w};
        v = b[i]; xb[i] = (bf16x4){(bf16)v.x, (bf16)v.y, (bf16)v.z, (bf16)v.w};
        v = c[i]; xc[i] = (bf16x4){(bf16)v.x, (bf16)v.y, (bf16)v.z, (bf16)v.w};
    }
}

// LDS-tiled transposes (coalesced reads AND writes).
// Head weights [16][1024][64] -> WT[(h*64+d)][1024]; Wo [1024][1024] -> WoT[n][f].
// grid (16,16): bx = m/f tile, by = h (heads) and n tile (Wo).
__global__ void transw(const float* __restrict__ wq, const float* __restrict__ wk,
                       const float* __restrict__ wv, const float* __restrict__ wo,
                       bf16* __restrict__ wqT, bf16* __restrict__ wkT,
                       bf16* __restrict__ wvT, bf16* __restrict__ woT)
{
    __shared__ float t[64][65];
    const int tid = threadIdx.x, bx = blockIdx.x, by = blockIdx.y;
    const float* srcs[3] = {wq, wk, wv};
    bf16* dsts[3] = {wqT, wkT, wvT};
#pragma unroll
    for (int m = 0; m < 3; ++m) {
        const float sc = (m == 0) ? 0.125f : 1.0f;   // fold 1/sqrt(KEY) into Wq
        for (int i = tid; i < 4096; i += 256) {
            int r = i >> 6, c = i & 63;              // r: m-sub, c: d
            t[c][r] = srcs[m][by * 65536 + (bx * 64 + r) * 64 + c];
        }
        __syncthreads();
        for (int i = tid; i < 4096; i += 256) {
            int r = i >> 6, c = i & 63;              // r: d, c: m-sub
            dsts[m][(long)(by * 64 + r) * 1024 + bx * 64 + c] = (bf16)(t[r][c] * sc);
        }
        __syncthreads();
    }
    for (int i = tid; i < 4096; i += 256) {          // Wo: f=bx*64+r rows, n=by*64+c
        int r = i >> 6, c = i & 63;
        t[c][r] = wo[(long)(bx * 64 + r) * 1024 + by * 64 + c];
    }
    __syncthreads();
    for (int i = tid; i < 4096; i += 256) {
        int r = i >> 6, c = i & 63;
        woT[(long)(by * 64 + r) * 1024 + bx * 64 + c] = (bf16)t[r][c];
    }
}

// ---------------------------------------------------------------------------
// GEMM: C[8192][1024] = A[8192][1024] * Bt[1024][1024]^T  (Bt n-major)
// Double-buffered K-tiles: one barrier per kt, prefetch in flight across it.
// MODE 0: bf16 out [b][h][s][64] ; MODE 1: bf16 out [b][h][64][s] ;
// MODE 2: f32 out + bias, row-major.
// ---------------------------------------------------------------------------
template<int MODE>
__global__ __launch_bounds__(256, 2) void gemm8k(const bf16* __restrict__ A,
                                                 const bf16* __restrict__ Bt,
                                                 bf16* __restrict__ Cb,
                                                 float* __restrict__ Cf,
                                                 const float* __restrict__ bias)
{
    __shared__ alignas(16) bf16 sA[2][128 * 64];
    __shared__ alignas(16) bf16 sB[2][128 * 64];
    const int tid = threadIdx.x, lane = tid & 63, wave = tid >> 6;
    const int wr = wave >> 1, wc = wave & 1;
    const long row0 = (long)blockIdx.x << 7;
    const long col0 = (long)blockIdx.y << 7;

    f32x4 acc[4][4];
#pragma unroll
    for (int i = 0; i < 4; ++i)
#pragma unroll
        for (int j = 0; j < 4; ++j) acc[i][j] = (f32x4){0.f, 0.f, 0.f, 0.f};

    stage_swz(A,  1024, row0, 0, sA[0], 128, tid);
    stage_swz(Bt, 1024, col0, 0, sB[0], 128, tid);

    for (int kt = 0; kt < 16; ++kt) {
        const int cur = kt & 1;
        __syncthreads();                             // drains vmcnt -> [cur] ready
        if (kt + 1 < 16) {
            stage_swz(A,  1024, row0, (long)(kt + 1) << 6, sA[cur ^ 1], 128, tid);
            stage_swz(Bt, 1024, col0, (long)(kt + 1) << 6, sB[cur ^ 1], 128, tid);
        }
#pragma unroll
        for (int kk = 0; kk < 2; ++kk) {
            bf16x8 af[4], bfr[4];
            const unsigned kb = (unsigned)(kk << 6) + (unsigned)((lane >> 4) << 4);
#pragma unroll
            for (int i = 0; i < 4; ++i) {
                unsigned r = (unsigned)((wr << 6) + (i << 4) + (lane & 15));
                af[i] = *(const bf16x8*)((const char*)sA[cur] + (r << 7) + (kb ^ ((r & 7u) << 4)));
            }
#pragma unroll
            for (int j = 0; j < 4; ++j) {
                unsigned r = (unsigned)((wc << 6) + (j << 4) + (lane & 15));
                bfr[j] = *(const bf16x8*)((const char*)sB[cur] + (r << 7) + (kb ^ ((r & 7u) << 4)));
            }
#pragma unroll
            for (int i = 0; i < 4; ++i)
#pragma unroll
                for (int j = 0; j < 4; ++j)
                    acc[i][j] = __builtin_amdgcn_mfma_f32_16x16x32_bf16(af[i], bfr[j], acc[i][j], 0, 0, 0);
        }
    }

#pragma unroll
    for (int i = 0; i < 4; ++i) {
#pragma unroll
        for (int j = 0; j < 4; ++j) {
#pragma unroll
            for (int rr = 0; rr < 4; ++rr) {
                long row = row0 + (wr << 6) + (i << 4) + ((lane >> 4) << 2) + rr;
                long col = col0 + (wc << 6) + (j << 4) + (lane & 15);
                float v = acc[i][j][rr];
                if constexpr (MODE == 2) {
                    Cf[row * 1024 + col] = v + bias[col];
                } else if constexpr (MODE == 0) {
                    long idx = (((row >> 11) << 4) + (col >> 6)) * 131072 + (row & 2047) * 64 + (col & 63);
                    Cb[idx] = (bf16)v;
                } else {
                    long idx = (((row >> 11) << 4) + (col >> 6)) * 131072 + (col & 63) * 2048 + (row & 2047);
                    Cb[idx] = (bf16)v;
                }
            }
        }
    }
}

// ---------------------------------------------------------------------------
// Flash causal attention. Grid = 1024 blocks, 4 waves each; one 128-row
// q-strip per block. XCD-chunked swizzle: swz=(bid&7)*128+(bid>>3) so each
// XCD's 128 blocks cover 8 (b,h) heads (KV ~4MB = its L2). qt=15-(swz&15)
// puts long strips first. KV double-buffered; row-sum l via ones-MFMA
// (rescales with accO automatically -> no shuffle sum-reduce).
// ---------------------------------------------------------------------------
__global__ __launch_bounds__(256, 3) void attn(const bf16* __restrict__ q,
                                               const bf16* __restrict__ k,
                                               const bf16* __restrict__ vT,
                                               bf16* __restrict__ o)
{
    __shared__ alignas(16) bf16 sK[2][64 * 64];
    __shared__ alignas(16) bf16 sV[2][64 * 64];
    __shared__ alignas(16) bf16 sP[4][32 * 72];     // per-wave, stride 72 (+8 pad)
    const int tid = threadIdx.x, lane = tid & 63, wave = tid >> 6;
    const int bid = blockIdx.x;
    const int swz = ((bid & 7) << 7) + (bid >> 3);
    const int qt = 15 - (swz & 15);
    const int hb = swz >> 4;                        // 0..63
    const int h = hb & 15, b = hb >> 4;
    const bf16* qh = q  + (long)hb * 131072;        // [2048][64]
    const bf16* kh = k  + (long)hb * 131072;        // [2048][64]
    const bf16* vh = vT + (long)hb * 131072;        // [64][2048]
    const int qw = (qt << 7) + (wave << 5);         // wave's first q row

    bf16x8 aq[2][2];
#pragma unroll
    for (int mf = 0; mf < 2; ++mf)
#pragma unroll
        for (int kk = 0; kk < 2; ++kk)
            aq[mf][kk] = *(const bf16x8*)(qh + (long)(qw + (mf << 4) + (lane & 15)) * 64
                                             + (kk << 5) + ((lane >> 4) << 3));
    bf16x8 vone;
#pragma unroll
    for (int i = 0; i < 8; ++i) vone[i] = (bf16)1.0f;

    f32x4 accO[2][4], accOl[2];
    float mrow[2][4];
#pragma unroll
    for (int mf = 0; mf < 2; ++mf) {
#pragma unroll
        for (int nf = 0; nf < 4; ++nf) accO[mf][nf] = (f32x4){0.f, 0.f, 0.f, 0.f};
        accOl[mf] = (f32x4){0.f, 0.f, 0.f, 0.f};
#pragma unroll
        for (int rr = 0; rr < 4; ++rr) mrow[mf][rr] = -1e30f;
    }

    const int nkv = (qt << 1) + 2;
    stage_swz(kh, 64,   0, 0, sK[0], 64, tid);
    stage_swz(vh, 2048, 0, 0, sV[0], 64, tid);

    for (int kvt = 0; kvt < nkv; ++kvt) {
        const int cur = kvt & 1;
        const int kv0 = kvt << 6;
        __syncthreads();                            // vmcnt drain -> sK/sV[cur] ready
        if (kvt + 1 < nkv) {                        // prefetch next into [cur^1]
            stage_swz(kh, 64,   (long)(kv0 + 64), 0, sK[cur ^ 1], 64, tid);
            stage_swz(vh, 2048, 0, (long)(kv0 + 64), sV[cur ^ 1], 64, tid);
        }
        if (kv0 > qw + 31) continue;                // fully masked for this wave

        // S = Q K^T
        f32x4 s[2][4];
#pragma unroll
        for (int mf = 0; mf < 2; ++mf)
#pragma unroll
            for (int nf = 0; nf < 4; ++nf) s[mf][nf] = (f32x4){0.f, 0.f, 0.f, 0.f};
#pragma unroll
        for (int kk = 0; kk < 2; ++kk) {
            bf16x8 bk[4];
            const unsigned kb = (unsigned)(kk << 6) + (unsigned)((lane >> 4) << 4);
#pragma unroll
            for (int nf = 0; nf < 4; ++nf) {
                unsigned r = (unsigned)((nf << 4) + (lane & 15));
                bk[nf] = *(const bf16x8*)((const char*)sK[cur] + (r << 7) + (kb ^ ((r & 7u) << 4)));
            }
#pragma unroll
            for (int mf = 0; mf < 2; ++mf)
#pragma unroll
                for (int nf = 0; nf < 4; ++nf)
                    s[mf][nf] = __builtin_amdgcn_mfma_f32_16x16x32_bf16(aq[mf][kk], bk[nf], s[mf][nf], 0, 0, 0);
        }

        // causal mask (diagonal tiles only)
        if (kv0 + 63 > qw) {
#pragma unroll
            for (int mf = 0; mf < 2; ++mf)
#pragma unroll
                for (int rr = 0; rr < 4; ++rr) {
                    const int ra = qw + (mf << 4) + ((lane >> 4) << 2) + rr;
#pragma unroll
                    for (int nf = 0; nf < 4; ++nf)
                        if ((kv0 + (nf << 4) + (lane & 15)) > ra) s[mf][nf][rr] = -1e30f;
                }
        }

        // online softmax: max-reduce (shfl), conditional rescale, exp2-domain P
#pragma unroll
        for (int mf = 0; mf < 2; ++mf) {
#pragma unroll
            for (int rr = 0; rr < 4; ++rr) {
                float mt = fmaxf(fmaxf(s[mf][0][rr], s[mf][1][rr]), fmaxf(s[mf][2][rr], s[mf][3][rr]));
                mt = fmaxf(mt, __shfl_xor(mt, 1));
                mt = fmaxf(mt, __shfl_xor(mt, 2));
                mt = fmaxf(mt, __shfl_xor(mt, 4));
                mt = fmaxf(mt, __shfl_xor(mt, 8));
                if (mt > mrow[mf][rr]) {            // uniform per 16-lane group
                    const float cf = __builtin_exp2f((mrow[mf][rr] - mt) * L2E);
                    mrow[mf][rr] = mt;
                    accOl[mf][rr] *= cf;
#pragma unroll
                    for (int nf = 0; nf < 4; ++nf) accO[mf][nf][rr] *= cf;
                }
                const float m2 = mrow[mf][rr] * L2E;
#pragma unroll
                for (int nf = 0; nf < 4; ++nf)
                    s[mf][nf][rr] = __builtin_exp2f(__builtin_fmaf(s[mf][nf][rr], L2E, -m2));
            }
        }

        // P -> per-wave LDS (C-layout scatter), then PV + ones-column (row sum)
        bf16* pw = &sP[wave][0];
#pragma unroll
        for (int mf = 0; mf < 2; ++mf)
#pragma unroll
            for (int nf = 0; nf < 4; ++nf)
#pragma unroll
                for (int rr = 0; rr < 4; ++rr)
                    pw[((mf << 4) + ((lane >> 4) << 2) + rr) * 72 + (nf << 4) + (lane & 15)] =
                        (bf16)s[mf][nf][rr];

#pragma unroll
        for (int kk = 0; kk < 2; ++kk) {
            bf16x8 pa[2], bv[4];
#pragma unroll
            for (int mf = 0; mf < 2; ++mf)
                pa[mf] = *(const bf16x8*)(pw + ((mf << 4) + (lane & 15)) * 72
                                             + (kk << 5) + ((lane >> 4) << 3));
            const unsigned kb = (unsigned)(kk << 6) + (unsigned)((lane >> 4) << 4);
#pragma unroll
            for (int nf = 0; nf < 4; ++nf) {
                unsigned r = (unsigned)((nf << 4) + (lane & 15));
                bv[nf] = *(const bf16x8*)((const char*)sV[cur] + (r << 7) + (kb ^ ((r & 7u) << 4)));
            }
#pragma unroll
            for (int mf = 0; mf < 2; ++mf) {
#pragma unroll
                for (int nf = 0; nf < 4; ++nf)
                    accO[mf][nf] = __builtin_amdgcn_mfma_f32_16x16x32_bf16(pa[mf], bv[nf], accO[mf][nf], 0, 0, 0);
                accOl[mf] = __builtin_amdgcn_mfma_f32_16x16x32_bf16(pa[mf], vone, accOl[mf], 0, 0, 0);
            }
        }
    }

    // O /= l ; write [b][s][h*64+d] bf16
#pragma unroll
    for (int mf = 0; mf < 2; ++mf)
#pragma unroll
        for (int rr = 0; rr < 4; ++rr) {
            const float inv = 1.f / accOl[mf][rr];
            const long ra = qw + (mf << 4) + ((lane >> 4) << 2) + rr;
#pragma unroll
            for (int nf = 0; nf < 4; ++nf)
                o[((long)b * 2048 + ra) * 1024 + (h << 6) + (nf << 4) + (lane & 15)] =
                    (bf16)(accO[mf][nf][rr] * inv);
        }
}

// ---------------------------------------------------------------------------
extern "C" void kernel_launch(void* const* d_in, const int* in_sizes, int n_in,
                              void* d_out, int out_size, void* d_ws, size_t ws_size,
                              hipStream_t stream)
{
    const float* queries = (const float*)d_in[0];
    const float* keys    = (const float*)d_in[1];
    const float* values  = (const float*)d_in[2];
    // d_in[3] = masks: statically causal, unused
    const float* Wq = (const float*)d_in[4];
    const float* Wk = (const float*)d_in[5];
    const float* Wv = (const float*)d_in[6];
    const float* Wo = (const float*)d_in[7];
    const float* bo = (const float*)d_in[8];
    float* out = (float*)d_out;

    bf16* Xq  = (bf16*)d_ws;          // 8192*1024
    bf16* Xk  = Xq  + 8388608;
    bf16* Xv  = Xk  + 8388608;
    bf16* WqT = Xv  + 8388608;        // 1024*1024 each
    bf16* WkT = WqT + 1048576;
    bf16* WvT = WkT + 1048576;
    bf16* WoT = WvT + 1048576;
    bf16* qp  = WoT + 1048576;        // [4][16][2048][64]
    bf16* kp  = qp  + 8388608;
    bf16* vTp = Xq;                   // [4][16][64][2048]  (alias, Xq dead after q-proj)
    bf16* ao  = Xk;                   // [8192][1024]       (alias, Xk dead after k-proj)
    if (ws_size < (size_t)92274688) return;

    cast3<<<dim3(2048), dim3(256), 0, stream>>>((const float4*)queries, (const float4*)keys,
                                                (const float4*)values,
                                                (bf16x4*)Xq, (bf16x4*)Xk, (bf16x4*)Xv);
    transw<<<dim3(16, 16), dim3(256), 0, stream>>>(Wq, Wk, Wv, Wo, WqT, WkT, WvT, WoT);
    gemm8k<0><<<dim3(64, 8), dim3(256), 0, stream>>>(Xq, WqT, qp,  nullptr, nullptr);
    gemm8k<0><<<dim3(64, 8), dim3(256), 0, stream>>>(Xk, WkT, kp,  nullptr, nullptr);
    gemm8k<1><<<dim3(64, 8), dim3(256), 0, stream>>>(Xv, WvT, vTp, nullptr, nullptr);
    attn<<<dim3(1024), dim3(256), 0, stream>>>(qp, kp, vTp, ao);
    gemm8k<2><<<dim3(64, 8), dim3(256), 0, stream>>>(ao, WoT, nullptr, out, bo);
}

// Round 7
// 441.031 us; speedup vs baseline: 1.0618x; 1.0618x over previous
//
#include <hip/hip_runtime.h>

// ---------------------------------------------------------------------------
// MultiHeadAttention: B=4 S=2048 MODEL=1024 H=16 Dk=Dv=64, causal.
// cast(QKV->bf16) ; LDS-tiled weight transpose (Wq pre-scaled 1/8) ;
// q,k proj GEMM (MODE0) ; v^T via swapped-operand GEMM (MODE3, coalesced) ;
// flash causal attn (paired strips = perfect balance, XCD-chunked KV,
// ones-MFMA row-sum) ; out GEMM (+bias, f32).
// Mask input is statically causal -> arithmetic.
// LDS tiles: 128B rows, XOR swizzle byte^=((row&7)<<4), global_load_lds(16B)
// from pre-swizzled global addresses (rule #21).
// ---------------------------------------------------------------------------

typedef __bf16 bf16;
typedef __attribute__((ext_vector_type(8))) __bf16 bf16x8;
typedef __attribute__((ext_vector_type(4))) __bf16 bf16x4;
typedef __attribute__((ext_vector_type(4))) float f32x4;
typedef unsigned int u32;

#define GLB_AS __attribute__((address_space(1)))
#define LDS_AS __attribute__((address_space(3)))

#define L2E 1.44269504088896340736f

static __device__ __forceinline__ void stage_swz(const bf16* __restrict__ g, long ldelem,
                                                 long row0, long col0,
                                                 bf16* lds, int rows, int tid)
{
    const int lane = tid & 63;
    const int wave = tid >> 6;
    const int nch = rows >> 3;                       // 1KB chunks
    for (int c = wave; c < nch; c += 4) {
        unsigned o  = ((unsigned)c << 10) + ((unsigned)lane << 4); // linear byte in tile
        unsigned r  = o >> 7;                         // tile row (128B/row)
        unsigned cb = o & 127u;                       // byte within row
        unsigned cs = cb ^ ((r & 7u) << 4);           // pre-swizzled source byte
        const bf16* src = g + (row0 + (long)r) * ldelem + col0 + (long)(cs >> 1);
        char* dst = (char*)lds + ((unsigned)c << 10); // wave-uniform, linear
        __builtin_amdgcn_global_load_lds((GLB_AS u32*)src, (LDS_AS u32*)dst, 16, 0, 0);
    }
}

// ---------------------------------------------------------------------------
// Prep kernels
// ---------------------------------------------------------------------------
__global__ void cast3(const float4* __restrict__ a, const float4* __restrict__ b,
                      const float4* __restrict__ c,
                      bf16x4* __restrict__ xa, bf16x4* __restrict__ xb,
                      bf16x4* __restrict__ xc)
{
    const int n4 = (8192 * 1024) / 4;
    for (int i = blockIdx.x * blockDim.x + threadIdx.x; i < n4; i += gridDim.x * blockDim.x) {
        float4 v;
        v = a[i]; xa[i] = (bf16x4){(bf16)v.x, (bf16)v.y, (bf16)v.z, (bf16)v.w};
        v = b[i]; xb[i] = (bf16x4){(bf16)v.x, (bf16)v.y, (bf16)v.z, (bf16)v.w};
        v = c[i]; xc[i] = (bf16x4){(bf16)v.x, (bf16)v.y, (bf16)v.z, (bf16)v.w};
    }
}

// LDS-tiled transposes (coalesced reads AND writes).
// Head weights [16][1024][64] -> WT[(h*64+d)][1024]; Wo [1024][1024] -> WoT[n][f].
__global__ void transw(const float* __restrict__ wq, const float* __restrict__ wk,
                       const float* __restrict__ wv, const float* __restrict__ wo,
                       bf16* __restrict__ wqT, bf16* __restrict__ wkT,
                       bf16* __restrict__ wvT, bf16* __restrict__ woT)
{
    __shared__ float t[64][65];
    const int tid = threadIdx.x, bx = blockIdx.x, by = blockIdx.y;
    const float* srcs[3] = {wq, wk, wv};
    bf16* dsts[3] = {wqT, wkT, wvT};
#pragma unroll
    for (int m = 0; m < 3; ++m) {
        const float sc = (m == 0) ? 0.125f : 1.0f;   // fold 1/sqrt(KEY) into Wq
        for (int i = tid; i < 4096; i += 256) {
            int r = i >> 6, c = i & 63;              // r: m-sub, c: d
            t[c][r] = srcs[m][by * 65536 + (bx * 64 + r) * 64 + c];
        }
        __syncthreads();
        for (int i = tid; i < 4096; i += 256) {
            int r = i >> 6, c = i & 63;              // r: d, c: m-sub
            dsts[m][(long)(by * 64 + r) * 1024 + bx * 64 + c] = (bf16)(t[r][c] * sc);
        }
        __syncthreads();
    }
    for (int i = tid; i < 4096; i += 256) {          // Wo: f=bx*64+r rows, n=by*64+c
        int r = i >> 6, c = i & 63;
        t[c][r] = wo[(long)(bx * 64 + r) * 1024 + by * 64 + c];
    }
    __syncthreads();
    for (int i = tid; i < 4096; i += 256) {
        int r = i >> 6, c = i & 63;
        woT[(long)(by * 64 + r) * 1024 + bx * 64 + c] = (bf16)t[r][c];
    }
}

// ---------------------------------------------------------------------------
// GEMM: C[M][N] = A[M][1024] * Bt[N][1024]^T  (Bt n-major), tile 128x128.
// MODE 0: bf16 out [b][h][s][64]           (q/k: M=8192 rows=s, N=1024 cols=hd)
// MODE 2: f32 out + bias, row-major        (out-proj)
// MODE 3: bf16 out vT [b][h][64][s]        (v: M=1024 rows=hd, N=8192 cols=bs;
//                                           s-contiguous -> coalesced)
// Double-buffered K-tiles: one barrier per kt, prefetch in flight across it.
// ---------------------------------------------------------------------------
template<int MODE>
__global__ __launch_bounds__(256, 2) void gemm8k(const bf16* __restrict__ A,
                                                 const bf16* __restrict__ Bt,
                                                 bf16* __restrict__ Cb,
                                                 float* __restrict__ Cf,
                                                 const float* __restrict__ bias)
{
    __shared__ alignas(16) bf16 sA[2][128 * 64];
    __shared__ alignas(16) bf16 sB[2][128 * 64];
    const int tid = threadIdx.x, lane = tid & 63, wave = tid >> 6;
    const int wr = wave >> 1, wc = wave & 1;
    const long row0 = (long)blockIdx.x << 7;
    const long col0 = (long)blockIdx.y << 7;

    f32x4 acc[4][4];
#pragma unroll
    for (int i = 0; i < 4; ++i)
#pragma unroll
        for (int j = 0; j < 4; ++j) acc[i][j] = (f32x4){0.f, 0.f, 0.f, 0.f};

    stage_swz(A,  1024, row0, 0, sA[0], 128, tid);
    stage_swz(Bt, 1024, col0, 0, sB[0], 128, tid);

    for (int kt = 0; kt < 16; ++kt) {
        const int cur = kt & 1;
        __syncthreads();                             // drains vmcnt -> [cur] ready
        if (kt + 1 < 16) {
            stage_swz(A,  1024, row0, (long)(kt + 1) << 6, sA[cur ^ 1], 128, tid);
            stage_swz(Bt, 1024, col0, (long)(kt + 1) << 6, sB[cur ^ 1], 128, tid);
        }
#pragma unroll
        for (int kk = 0; kk < 2; ++kk) {
            bf16x8 af[4], bfr[4];
            const unsigned kb = (unsigned)(kk << 6) + (unsigned)((lane >> 4) << 4);
#pragma unroll
            for (int i = 0; i < 4; ++i) {
                unsigned r = (unsigned)((wr << 6) + (i << 4) + (lane & 15));
                af[i] = *(const bf16x8*)((const char*)sA[cur] + (r << 7) + (kb ^ ((r & 7u) << 4)));
            }
#pragma unroll
            for (int j = 0; j < 4; ++j) {
                unsigned r = (unsigned)((wc << 6) + (j << 4) + (lane & 15));
                bfr[j] = *(const bf16x8*)((const char*)sB[cur] + (r << 7) + (kb ^ ((r & 7u) << 4)));
            }
#pragma unroll
            for (int i = 0; i < 4; ++i)
#pragma unroll
                for (int j = 0; j < 4; ++j)
                    acc[i][j] = __builtin_amdgcn_mfma_f32_16x16x32_bf16(af[i], bfr[j], acc[i][j], 0, 0, 0);
        }
    }

#pragma unroll
    for (int i = 0; i < 4; ++i) {
#pragma unroll
        for (int j = 0; j < 4; ++j) {
#pragma unroll
            for (int rr = 0; rr < 4; ++rr) {
                long row = row0 + (wr << 6) + (i << 4) + ((lane >> 4) << 2) + rr;
                long col = col0 + (wc << 6) + (j << 4) + (lane & 15);
                float v = acc[i][j][rr];
                if constexpr (MODE == 2) {
                    Cf[row * 1024 + col] = v + bias[col];
                } else if constexpr (MODE == 0) {
                    // row = b*2048+s, col = h*64+d
                    long idx = (((row >> 11) << 4) + (col >> 6)) * 131072 + (row & 2047) * 64 + (col & 63);
                    Cb[idx] = (bf16)v;
                } else {
                    // MODE 3: row = h*64+d, col = b*2048+s
                    long idx = ((((col >> 11) << 4) + (row >> 6)) * 64 + (row & 63)) * 2048 + (col & 2047);
                    Cb[idx] = (bf16)v;
                }
            }
        }
    }
}

// ---------------------------------------------------------------------------
// Flash causal attention, paired strips + XCD-chunked KV locality.
// Grid 512, 4 waves. bid -> xcd=bid&7, idx=bid>>3 ; hb=xcd*8+(idx&7) so each
// XCD's 64 blocks share 8 heads' KV (~4MB = its L2) ; pair=idx>>3 ->
// strips qt=pair and 15-pair -> every block exactly 34 KV tiles (balanced).
// KV double-buffered (one barrier/tile); ones-MFMA row-sum (no shuffle sum);
// exp2-domain P; rescale only when row max grows. Wq pre-scaled by 1/8.
// ---------------------------------------------------------------------------
__global__ __launch_bounds__(256, 2) void attn(const bf16* __restrict__ q,
                                               const bf16* __restrict__ k,
                                               const bf16* __restrict__ vT,
                                               bf16* __restrict__ o)
{
    __shared__ alignas(16) bf16 sK[2][64 * 64];
    __shared__ alignas(16) bf16 sV[2][64 * 64];
    __shared__ alignas(16) bf16 sP[4][32 * 72];     // per-wave, stride 72 (+8 pad)
    const int tid = threadIdx.x, lane = tid & 63, wave = tid >> 6;
    const int bid = blockIdx.x;
    const int hb = ((bid & 7) << 3) + ((bid >> 3) & 7);
    const int pair = bid >> 6;                      // 0..7
    const int h = hb & 15, b = hb >> 4;
    const bf16* qh = q  + (long)hb * 131072;        // [2048][64]
    const bf16* kh = k  + (long)hb * 131072;        // [2048][64]
    const bf16* vh = vT + (long)hb * 131072;        // [64][2048]

    bf16x8 vone;
#pragma unroll
    for (int i = 0; i < 8; ++i) vone[i] = (bf16)1.0f;

    for (int half = 0; half < 2; ++half) {
        const int qt = half ? (15 - pair) : pair;
        const int qw = (qt << 7) + (wave << 5);     // wave's first q row

        bf16x8 aq[2][2];
#pragma unroll
        for (int mf = 0; mf < 2; ++mf)
#pragma unroll
            for (int kk = 0; kk < 2; ++kk)
                aq[mf][kk] = *(const bf16x8*)(qh + (long)(qw + (mf << 4) + (lane & 15)) * 64
                                                 + (kk << 5) + ((lane >> 4) << 3));

        f32x4 accO[2][4], accOl[2];
        float mrow[2][4];
#pragma unroll
        for (int mf = 0; mf < 2; ++mf) {
#pragma unroll
            for (int nf = 0; nf < 4; ++nf) accO[mf][nf] = (f32x4){0.f, 0.f, 0.f, 0.f};
            accOl[mf] = (f32x4){0.f, 0.f, 0.f, 0.f};
#pragma unroll
            for (int rr = 0; rr < 4; ++rr) mrow[mf][rr] = -1e30f;
        }

        const int nkv = (qt << 1) + 2;
        __syncthreads();                            // prev strip's readers done
        stage_swz(kh, 64,   0, 0, sK[0], 64, tid);
        stage_swz(vh, 2048, 0, 0, sV[0], 64, tid);

        for (int kvt = 0; kvt < nkv; ++kvt) {
            const int cur = kvt & 1;
            const int kv0 = kvt << 6;
            __syncthreads();                        // vmcnt drain -> sK/sV[cur] ready
            if (kvt + 1 < nkv) {                    // prefetch next into [cur^1]
                stage_swz(kh, 64,   (long)(kv0 + 64), 0, sK[cur ^ 1], 64, tid);
                stage_swz(vh, 2048, 0, (long)(kv0 + 64), sV[cur ^ 1], 64, tid);
            }
            if (kv0 > qw + 31) continue;            // fully masked for this wave

            // S = Q K^T
            f32x4 s[2][4];
#pragma unroll
            for (int mf = 0; mf < 2; ++mf)
#pragma unroll
                for (int nf = 0; nf < 4; ++nf) s[mf][nf] = (f32x4){0.f, 0.f, 0.f, 0.f};
#pragma unroll
            for (int kk = 0; kk < 2; ++kk) {
                bf16x8 bk[4];
                const unsigned kb = (unsigned)(kk << 6) + (unsigned)((lane >> 4) << 4);
#pragma unroll
                for (int nf = 0; nf < 4; ++nf) {
                    unsigned r = (unsigned)((nf << 4) + (lane & 15));
                    bk[nf] = *(const bf16x8*)((const char*)sK[cur] + (r << 7) + (kb ^ ((r & 7u) << 4)));
                }
#pragma unroll
                for (int mf = 0; mf < 2; ++mf)
#pragma unroll
                    for (int nf = 0; nf < 4; ++nf)
                        s[mf][nf] = __builtin_amdgcn_mfma_f32_16x16x32_bf16(aq[mf][kk], bk[nf], s[mf][nf], 0, 0, 0);
            }

            // causal mask (diagonal tiles only)
            if (kv0 + 63 > qw) {
#pragma unroll
                for (int mf = 0; mf < 2; ++mf)
#pragma unroll
                    for (int rr = 0; rr < 4; ++rr) {
                        const int ra = qw + (mf << 4) + ((lane >> 4) << 2) + rr;
#pragma unroll
                        for (int nf = 0; nf < 4; ++nf)
                            if ((kv0 + (nf << 4) + (lane & 15)) > ra) s[mf][nf][rr] = -1e30f;
                    }
            }

            // online softmax: max-reduce (shfl), conditional rescale, exp2 P
#pragma unroll
            for (int mf = 0; mf < 2; ++mf) {
#pragma unroll
                for (int rr = 0; rr < 4; ++rr) {
                    float mt = fmaxf(fmaxf(s[mf][0][rr], s[mf][1][rr]), fmaxf(s[mf][2][rr], s[mf][3][rr]));
                    mt = fmaxf(mt, __shfl_xor(mt, 1));
                    mt = fmaxf(mt, __shfl_xor(mt, 2));
                    mt = fmaxf(mt, __shfl_xor(mt, 4));
                    mt = fmaxf(mt, __shfl_xor(mt, 8));
                    if (mt > mrow[mf][rr]) {        // uniform per 16-lane group
                        const float cf = __builtin_exp2f((mrow[mf][rr] - mt) * L2E);
                        mrow[mf][rr] = mt;
                        accOl[mf][rr] *= cf;
#pragma unroll
                        for (int nf = 0; nf < 4; ++nf) accO[mf][nf][rr] *= cf;
                    }
                    const float m2 = mrow[mf][rr] * L2E;
#pragma unroll
                    for (int nf = 0; nf < 4; ++nf)
                        s[mf][nf][rr] = __builtin_exp2f(__builtin_fmaf(s[mf][nf][rr], L2E, -m2));
                }
            }

            // P -> per-wave LDS (C-layout scatter), then PV + ones-column
            bf16* pw = &sP[wave][0];
#pragma unroll
            for (int mf = 0; mf < 2; ++mf)
#pragma unroll
                for (int nf = 0; nf < 4; ++nf)
#pragma unroll
                    for (int rr = 0; rr < 4; ++rr)
                        pw[((mf << 4) + ((lane >> 4) << 2) + rr) * 72 + (nf << 4) + (lane & 15)] =
                            (bf16)s[mf][nf][rr];

#pragma unroll
            for (int kk = 0; kk < 2; ++kk) {
                bf16x8 pa[2], bv[4];
#pragma unroll
                for (int mf = 0; mf < 2; ++mf)
                    pa[mf] = *(const bf16x8*)(pw + ((mf << 4) + (lane & 15)) * 72
                                                 + (kk << 5) + ((lane >> 4) << 3));
                const unsigned kb = (unsigned)(kk << 6) + (unsigned)((lane >> 4) << 4);
#pragma unroll
                for (int nf = 0; nf < 4; ++nf) {
                    unsigned r = (unsigned)((nf << 4) + (lane & 15));
                    bv[nf] = *(const bf16x8*)((const char*)sV[cur] + (r << 7) + (kb ^ ((r & 7u) << 4)));
                }
#pragma unroll
                for (int mf = 0; mf < 2; ++mf) {
#pragma unroll
                    for (int nf = 0; nf < 4; ++nf)
                        accO[mf][nf] = __builtin_amdgcn_mfma_f32_16x16x32_bf16(pa[mf], bv[nf], accO[mf][nf], 0, 0, 0);
                    accOl[mf] = __builtin_amdgcn_mfma_f32_16x16x32_bf16(pa[mf], vone, accOl[mf], 0, 0, 0);
                }
            }
        }

        // O /= l ; write [b][s][h*64+d] bf16
#pragma unroll
        for (int mf = 0; mf < 2; ++mf)
#pragma unroll
            for (int rr = 0; rr < 4; ++rr) {
                const float inv = 1.f / accOl[mf][rr];
                const long ra = qw + (mf << 4) + ((lane >> 4) << 2) + rr;
#pragma unroll
                for (int nf = 0; nf < 4; ++nf)
                    o[((long)b * 2048 + ra) * 1024 + (h << 6) + (nf << 4) + (lane & 15)] =
                        (bf16)(accO[mf][nf][rr] * inv);
            }
    }
}

// ---------------------------------------------------------------------------
extern "C" void kernel_launch(void* const* d_in, const int* in_sizes, int n_in,
                              void* d_out, int out_size, void* d_ws, size_t ws_size,
                              hipStream_t stream)
{
    const float* queries = (const float*)d_in[0];
    const float* keys    = (const float*)d_in[1];
    const float* values  = (const float*)d_in[2];
    // d_in[3] = masks: statically causal, unused
    const float* Wq = (const float*)d_in[4];
    const float* Wk = (const float*)d_in[5];
    const float* Wv = (const float*)d_in[6];
    const float* Wo = (const float*)d_in[7];
    const float* bo = (const float*)d_in[8];
    float* out = (float*)d_out;

    bf16* Xq  = (bf16*)d_ws;          // 8192*1024
    bf16* Xk  = Xq  + 8388608;
    bf16* Xv  = Xk  + 8388608;
    bf16* WqT = Xv  + 8388608;        // 1024*1024 each
    bf16* WkT = WqT + 1048576;
    bf16* WvT = WkT + 1048576;
    bf16* WoT = WvT + 1048576;
    bf16* qp  = WoT + 1048576;        // [4][16][2048][64]
    bf16* kp  = qp  + 8388608;
    bf16* vTp = Xq;                   // [4][16][64][2048]  (alias, Xq dead after q-proj)
    bf16* ao  = Xk;                   // [8192][1024]       (alias, Xk dead after k-proj)
    if (ws_size < (size_t)92274688) return;

    cast3<<<dim3(2048), dim3(256), 0, stream>>>((const float4*)queries, (const float4*)keys,
                                                (const float4*)values,
                                                (bf16x4*)Xq, (bf16x4*)Xk, (bf16x4*)Xv);
    transw<<<dim3(16, 16), dim3(256), 0, stream>>>(Wq, Wk, Wv, Wo, WqT, WkT, WvT, WoT);
    gemm8k<0><<<dim3(64, 8), dim3(256), 0, stream>>>(Xq, WqT, qp,  nullptr, nullptr);
    gemm8k<0><<<dim3(64, 8), dim3(256), 0, stream>>>(Xk, WkT, kp,  nullptr, nullptr);
    gemm8k<3><<<dim3(8, 64), dim3(256), 0, stream>>>(WvT, Xv, vTp, nullptr, nullptr);
    attn<<<dim3(512), dim3(256), 0, stream>>>(qp, kp, vTp, ao);
    gemm8k<2><<<dim3(64, 8), dim3(256), 0, stream>>>(ao, WoT, nullptr, out, bo);
}

// Round 8
// 440.345 us; speedup vs baseline: 1.0635x; 1.0016x over previous
//
#include <hip/hip_runtime.h>

// ---------------------------------------------------------------------------
// MultiHeadAttention: B=4 S=2048 MODEL=1024 H=16 Dk=Dv=64, causal.
// cast(QKV->bf16) ; LDS-tiled weight transpose (Wq pre-scaled 1/8) ;
// FUSED qkv proj GEMM (one dispatch, 1536 blocks, single-buffer 32KB LDS,
// 3 blocks/CU) ; flash causal attn (paired strips, XCD-chunked KV, ones-MFMA
// row-sum) ; out GEMM (+bias, f32, single-buffer).
// Mask input is statically causal -> arithmetic.
// LDS tiles: 128B rows, XOR swizzle byte^=((row&7)<<4), global_load_lds(16B)
// from pre-swizzled global addresses (rule #21).
// ---------------------------------------------------------------------------

typedef __bf16 bf16;
typedef __attribute__((ext_vector_type(8))) __bf16 bf16x8;
typedef __attribute__((ext_vector_type(4))) __bf16 bf16x4;
typedef __attribute__((ext_vector_type(4))) float f32x4;
typedef unsigned int u32;

#define GLB_AS __attribute__((address_space(1)))
#define LDS_AS __attribute__((address_space(3)))

#define L2E 1.44269504088896340736f

static __device__ __forceinline__ void stage_swz(const bf16* __restrict__ g, long ldelem,
                                                 long row0, long col0,
                                                 bf16* lds, int rows, int tid)
{
    const int lane = tid & 63;
    const int wave = tid >> 6;
    const int nch = rows >> 3;                       // 1KB chunks
    for (int c = wave; c < nch; c += 4) {
        unsigned o  = ((unsigned)c << 10) + ((unsigned)lane << 4); // linear byte in tile
        unsigned r  = o >> 7;                         // tile row (128B/row)
        unsigned cb = o & 127u;                       // byte within row
        unsigned cs = cb ^ ((r & 7u) << 4);           // pre-swizzled source byte
        const bf16* src = g + (row0 + (long)r) * ldelem + col0 + (long)(cs >> 1);
        char* dst = (char*)lds + ((unsigned)c << 10); // wave-uniform, linear
        __builtin_amdgcn_global_load_lds((GLB_AS u32*)src, (LDS_AS u32*)dst, 16, 0, 0);
    }
}

// ---------------------------------------------------------------------------
// Prep kernels
// ---------------------------------------------------------------------------
__global__ void cast3(const float4* __restrict__ a, const float4* __restrict__ b,
                      const float4* __restrict__ c,
                      bf16x4* __restrict__ xa, bf16x4* __restrict__ xb,
                      bf16x4* __restrict__ xc)
{
    const int n4 = (8192 * 1024) / 4;
    for (int i = blockIdx.x * blockDim.x + threadIdx.x; i < n4; i += gridDim.x * blockDim.x) {
        float4 v;
        v = a[i]; xa[i] = (bf16x4){(bf16)v.x, (bf16)v.y, (bf16)v.z, (bf16)v.w};
        v = b[i]; xb[i] = (bf16x4){(bf16)v.x, (bf16)v.y, (bf16)v.z, (bf16)v.w};
        v = c[i]; xc[i] = (bf16x4){(bf16)v.x, (bf16)v.y, (bf16)v.z, (bf16)v.w};
    }
}

// LDS-tiled transposes (coalesced reads AND writes).
// Head weights [16][1024][64] -> WT[(h*64+d)][1024]; Wo [1024][1024] -> WoT[n][f].
__global__ void transw(const float* __restrict__ wq, const float* __restrict__ wk,
                       const float* __restrict__ wv, const float* __restrict__ wo,
                       bf16* __restrict__ wqT, bf16* __restrict__ wkT,
                       bf16* __restrict__ wvT, bf16* __restrict__ woT)
{
    __shared__ float t[64][65];
    const int tid = threadIdx.x, bx = blockIdx.x, by = blockIdx.y;
    const float* srcs[3] = {wq, wk, wv};
    bf16* dsts[3] = {wqT, wkT, wvT};
#pragma unroll
    for (int m = 0; m < 3; ++m) {
        const float sc = (m == 0) ? 0.125f : 1.0f;   // fold 1/sqrt(KEY) into Wq
        for (int i = tid; i < 4096; i += 256) {
            int r = i >> 6, c = i & 63;              // r: m-sub, c: d
            t[c][r] = srcs[m][by * 65536 + (bx * 64 + r) * 64 + c];
        }
        __syncthreads();
        for (int i = tid; i < 4096; i += 256) {
            int r = i >> 6, c = i & 63;              // r: d, c: m-sub
            dsts[m][(long)(by * 64 + r) * 1024 + bx * 64 + c] = (bf16)(t[r][c] * sc);
        }
        __syncthreads();
    }
    for (int i = tid; i < 4096; i += 256) {          // Wo: f=bx*64+r rows, n=by*64+c
        int r = i >> 6, c = i & 63;
        t[c][r] = wo[(long)(bx * 64 + r) * 1024 + by * 64 + c];
    }
    __syncthreads();
    for (int i = tid; i < 4096; i += 256) {
        int r = i >> 6, c = i & 63;
        woT[(long)(by * 64 + r) * 1024 + bx * 64 + c] = (bf16)t[r][c];
    }
}

// ---------------------------------------------------------------------------
// GEMM body: C[M][N] tile (128x128) = A[row0..][1024] * Bt[col0..][1024]^T.
// Single-buffered (32KB LDS) m97-style 2-barrier loop -> 3+ blocks/CU.
// MODE 0: bf16 out [b][h][s][64] ; MODE 2: f32 out + bias, row-major ;
// MODE 3: bf16 out vT [b][h][64][s] (row=hd, col=bs; s-contiguous).
// ---------------------------------------------------------------------------
template<int MODE>
static __device__ __forceinline__ void gemm_body(const bf16* __restrict__ A,
                                                 const bf16* __restrict__ Bt,
                                                 bf16* __restrict__ Cb,
                                                 float* __restrict__ Cf,
                                                 const float* __restrict__ bias,
                                                 long row0, long col0,
                                                 bf16* sA, bf16* sB)
{
    const int tid = threadIdx.x, lane = tid & 63, wave = tid >> 6;
    const int wr = wave >> 1, wc = wave & 1;

    f32x4 acc[4][4];
#pragma unroll
    for (int i = 0; i < 4; ++i)
#pragma unroll
        for (int j = 0; j < 4; ++j) acc[i][j] = (f32x4){0.f, 0.f, 0.f, 0.f};

    for (int kt = 0; kt < 16; ++kt) {
        __syncthreads();                             // prev-iter readers done
        stage_swz(A,  1024, row0, (long)kt << 6, sA, 128, tid);
        stage_swz(Bt, 1024, col0, (long)kt << 6, sB, 128, tid);
        __syncthreads();                             // vmcnt drain -> tiles ready
#pragma unroll
        for (int kk = 0; kk < 2; ++kk) {
            bf16x8 af[4], bfr[4];
            const unsigned kb = (unsigned)(kk << 6) + (unsigned)((lane >> 4) << 4);
#pragma unroll
            for (int i = 0; i < 4; ++i) {
                unsigned r = (unsigned)((wr << 6) + (i << 4) + (lane & 15));
                af[i] = *(const bf16x8*)((const char*)sA + (r << 7) + (kb ^ ((r & 7u) << 4)));
            }
#pragma unroll
            for (int j = 0; j < 4; ++j) {
                unsigned r = (unsigned)((wc << 6) + (j << 4) + (lane & 15));
                bfr[j] = *(const bf16x8*)((const char*)sB + (r << 7) + (kb ^ ((r & 7u) << 4)));
            }
#pragma unroll
            for (int i = 0; i < 4; ++i)
#pragma unroll
                for (int j = 0; j < 4; ++j)
                    acc[i][j] = __builtin_amdgcn_mfma_f32_16x16x32_bf16(af[i], bfr[j], acc[i][j], 0, 0, 0);
        }
    }

#pragma unroll
    for (int i = 0; i < 4; ++i) {
#pragma unroll
        for (int j = 0; j < 4; ++j) {
#pragma unroll
            for (int rr = 0; rr < 4; ++rr) {
                long row = row0 + (wr << 6) + (i << 4) + ((lane >> 4) << 2) + rr;
                long col = col0 + (wc << 6) + (j << 4) + (lane & 15);
                float v = acc[i][j][rr];
                if constexpr (MODE == 2) {
                    Cf[row * 1024 + col] = v + bias[col];
                } else if constexpr (MODE == 0) {
                    // row = b*2048+s, col = h*64+d
                    long idx = (((row >> 11) << 4) + (col >> 6)) * 131072 + (row & 2047) * 64 + (col & 63);
                    Cb[idx] = (bf16)v;
                } else {
                    // MODE 3: row = h*64+d, col = b*2048+s
                    long idx = ((((col >> 11) << 4) + (row >> 6)) * 64 + (row & 63)) * 2048 + (col & 2047);
                    Cb[idx] = (bf16)v;
                }
            }
        }
    }
}

// Fused q/k/v projections: grid (512, 3). op 0: q (64x8 tiles), op 1: k,
// op 2: v^T swapped-operand (8x64 tiles). 1536 blocks in one dispatch.
__global__ __launch_bounds__(256, 3) void gemm_qkv(const bf16* __restrict__ Xq, const bf16* __restrict__ WqT, bf16* __restrict__ qp,
                                                   const bf16* __restrict__ Xk, const bf16* __restrict__ WkT, bf16* __restrict__ kp,
                                                   const bf16* __restrict__ WvT, const bf16* __restrict__ Xv, bf16* __restrict__ vTp)
{
    __shared__ alignas(16) bf16 sA[128 * 64];
    __shared__ alignas(16) bf16 sB[128 * 64];
    const int bx = blockIdx.x;
    if (blockIdx.y == 0)
        gemm_body<0>(Xq, WqT, qp, nullptr, nullptr, (long)(bx >> 3) << 7, (long)(bx & 7) << 7, sA, sB);
    else if (blockIdx.y == 1)
        gemm_body<0>(Xk, WkT, kp, nullptr, nullptr, (long)(bx >> 3) << 7, (long)(bx & 7) << 7, sA, sB);
    else
        gemm_body<3>(WvT, Xv, vTp, nullptr, nullptr, (long)(bx & 7) << 7, (long)(bx >> 3) << 7, sA, sB);
}

// Output projection (+bias, f32): grid (64, 8).
__global__ __launch_bounds__(256, 3) void gemm_out(const bf16* __restrict__ A, const bf16* __restrict__ Bt,
                                                   float* __restrict__ Cf, const float* __restrict__ bias)
{
    __shared__ alignas(16) bf16 sA[128 * 64];
    __shared__ alignas(16) bf16 sB[128 * 64];
    gemm_body<2>(A, Bt, nullptr, Cf, bias, (long)blockIdx.x << 7, (long)blockIdx.y << 7, sA, sB);
}

// ---------------------------------------------------------------------------
// Flash causal attention, paired strips + XCD-chunked KV locality.
// Grid 512, 4 waves. bid -> xcd=bid&7, idx=bid>>3 ; hb=xcd*8+(idx&7) so each
// XCD's 64 blocks share 8 heads' KV (~4MB = its L2) ; pair=idx>>3 ->
// strips qt=pair and 15-pair -> every block exactly 34 KV tiles (balanced).
// KV double-buffered (one barrier/tile); ones-MFMA row-sum (no shuffle sum);
// exp2-domain P; rescale only when row max grows. Wq pre-scaled by 1/8.
// ---------------------------------------------------------------------------
__global__ __launch_bounds__(256, 2) void attn(const bf16* __restrict__ q,
                                               const bf16* __restrict__ k,
                                               const bf16* __restrict__ vT,
                                               bf16* __restrict__ o)
{
    __shared__ alignas(16) bf16 sK[2][64 * 64];
    __shared__ alignas(16) bf16 sV[2][64 * 64];
    __shared__ alignas(16) bf16 sP[4][32 * 72];     // per-wave, stride 72 (+8 pad)
    const int tid = threadIdx.x, lane = tid & 63, wave = tid >> 6;
    const int bid = blockIdx.x;
    const int hb = ((bid & 7) << 3) + ((bid >> 3) & 7);
    const int pair = bid >> 6;                      // 0..7
    const int h = hb & 15, b = hb >> 4;
    const bf16* qh = q  + (long)hb * 131072;        // [2048][64]
    const bf16* kh = k  + (long)hb * 131072;        // [2048][64]
    const bf16* vh = vT + (long)hb * 131072;        // [64][2048]

    bf16x8 vone;
#pragma unroll
    for (int i = 0; i < 8; ++i) vone[i] = (bf16)1.0f;

    for (int half = 0; half < 2; ++half) {
        const int qt = half ? (15 - pair) : pair;
        const int qw = (qt << 7) + (wave << 5);     // wave's first q row

        bf16x8 aq[2][2];
#pragma unroll
        for (int mf = 0; mf < 2; ++mf)
#pragma unroll
            for (int kk = 0; kk < 2; ++kk)
                aq[mf][kk] = *(const bf16x8*)(qh + (long)(qw + (mf << 4) + (lane & 15)) * 64
                                                 + (kk << 5) + ((lane >> 4) << 3));

        f32x4 accO[2][4], accOl[2];
        float mrow[2][4];
#pragma unroll
        for (int mf = 0; mf < 2; ++mf) {
#pragma unroll
            for (int nf = 0; nf < 4; ++nf) accO[mf][nf] = (f32x4){0.f, 0.f, 0.f, 0.f};
            accOl[mf] = (f32x4){0.f, 0.f, 0.f, 0.f};
#pragma unroll
            for (int rr = 0; rr < 4; ++rr) mrow[mf][rr] = -1e30f;
        }

        const int nkv = (qt << 1) + 2;
        __syncthreads();                            // prev strip's readers done
        stage_swz(kh, 64,   0, 0, sK[0], 64, tid);
        stage_swz(vh, 2048, 0, 0, sV[0], 64, tid);

        for (int kvt = 0; kvt < nkv; ++kvt) {
            const int cur = kvt & 1;
            const int kv0 = kvt << 6;
            __syncthreads();                        // vmcnt drain -> sK/sV[cur] ready
            if (kvt + 1 < nkv) {                    // prefetch next into [cur^1]
                stage_swz(kh, 64,   (long)(kv0 + 64), 0, sK[cur ^ 1], 64, tid);
                stage_swz(vh, 2048, 0, (long)(kv0 + 64), sV[cur ^ 1], 64, tid);
            }
            if (kv0 > qw + 31) continue;            // fully masked for this wave

            // S = Q K^T
            f32x4 s[2][4];
#pragma unroll
            for (int mf = 0; mf < 2; ++mf)
#pragma unroll
                for (int nf = 0; nf < 4; ++nf) s[mf][nf] = (f32x4){0.f, 0.f, 0.f, 0.f};
#pragma unroll
            for (int kk = 0; kk < 2; ++kk) {
                bf16x8 bk[4];
                const unsigned kb = (unsigned)(kk << 6) + (unsigned)((lane >> 4) << 4);
#pragma unroll
                for (int nf = 0; nf < 4; ++nf) {
                    unsigned r = (unsigned)((nf << 4) + (lane & 15));
                    bk[nf] = *(const bf16x8*)((const char*)sK[cur] + (r << 7) + (kb ^ ((r & 7u) << 4)));
                }
#pragma unroll
                for (int mf = 0; mf < 2; ++mf)
#pragma unroll
                    for (int nf = 0; nf < 4; ++nf)
                        s[mf][nf] = __builtin_amdgcn_mfma_f32_16x16x32_bf16(aq[mf][kk], bk[nf], s[mf][nf], 0, 0, 0);
            }

            // causal mask (diagonal tiles only)
            if (kv0 + 63 > qw) {
#pragma unroll
                for (int mf = 0; mf < 2; ++mf)
#pragma unroll
                    for (int rr = 0; rr < 4; ++rr) {
                        const int ra = qw + (mf << 4) + ((lane >> 4) << 2) + rr;
#pragma unroll
                        for (int nf = 0; nf < 4; ++nf)
                            if ((kv0 + (nf << 4) + (lane & 15)) > ra) s[mf][nf][rr] = -1e30f;
                    }
            }

            // online softmax: max-reduce (shfl), conditional rescale, exp2 P
#pragma unroll
            for (int mf = 0; mf < 2; ++mf) {
#pragma unroll
                for (int rr = 0; rr < 4; ++rr) {
                    float mt = fmaxf(fmaxf(s[mf][0][rr], s[mf][1][rr]), fmaxf(s[mf][2][rr], s[mf][3][rr]));
                    mt = fmaxf(mt, __shfl_xor(mt, 1));
                    mt = fmaxf(mt, __shfl_xor(mt, 2));
                    mt = fmaxf(mt, __shfl_xor(mt, 4));
                    mt = fmaxf(mt, __shfl_xor(mt, 8));
                    if (mt > mrow[mf][rr]) {        // uniform per 16-lane group
                        const float cf = __builtin_exp2f((mrow[mf][rr] - mt) * L2E);
                        mrow[mf][rr] = mt;
                        accOl[mf][rr] *= cf;
#pragma unroll
                        for (int nf = 0; nf < 4; ++nf) accO[mf][nf][rr] *= cf;
                    }
                    const float m2 = mrow[mf][rr] * L2E;
#pragma unroll
                    for (int nf = 0; nf < 4; ++nf)
                        s[mf][nf][rr] = __builtin_exp2f(__builtin_fmaf(s[mf][nf][rr], L2E, -m2));
                }
            }

            // P -> per-wave LDS (C-layout scatter), then PV + ones-column
            bf16* pw = &sP[wave][0];
#pragma unroll
            for (int mf = 0; mf < 2; ++mf)
#pragma unroll
                for (int nf = 0; nf < 4; ++nf)
#pragma unroll
                    for (int rr = 0; rr < 4; ++rr)
                        pw[((mf << 4) + ((lane >> 4) << 2) + rr) * 72 + (nf << 4) + (lane & 15)] =
                            (bf16)s[mf][nf][rr];

#pragma unroll
            for (int kk = 0; kk < 2; ++kk) {
                bf16x8 pa[2], bv[4];
#pragma unroll
                for (int mf = 0; mf < 2; ++mf)
                    pa[mf] = *(const bf16x8*)(pw + ((mf << 4) + (lane & 15)) * 72
                                                 + (kk << 5) + ((lane >> 4) << 3));
                const unsigned kb = (unsigned)(kk << 6) + (unsigned)((lane >> 4) << 4);
#pragma unroll
                for (int nf = 0; nf < 4; ++nf) {
                    unsigned r = (unsigned)((nf << 4) + (lane & 15));
                    bv[nf] = *(const bf16x8*)((const char*)sV[cur] + (r << 7) + (kb ^ ((r & 7u) << 4)));
                }
#pragma unroll
                for (int mf = 0; mf < 2; ++mf) {
#pragma unroll
                    for (int nf = 0; nf < 4; ++nf)
                        accO[mf][nf] = __builtin_amdgcn_mfma_f32_16x16x32_bf16(pa[mf], bv[nf], accO[mf][nf], 0, 0, 0);
                    accOl[mf] = __builtin_amdgcn_mfma_f32_16x16x32_bf16(pa[mf], vone, accOl[mf], 0, 0, 0);
                }
            }
        }

        // O /= l ; write [b][s][h*64+d] bf16
#pragma unroll
        for (int mf = 0; mf < 2; ++mf)
#pragma unroll
            for (int rr = 0; rr < 4; ++rr) {
                const float inv = 1.f / accOl[mf][rr];
                const long ra = qw + (mf << 4) + ((lane >> 4) << 2) + rr;
#pragma unroll
                for (int nf = 0; nf < 4; ++nf)
                    o[((long)b * 2048 + ra) * 1024 + (h << 6) + (nf << 4) + (lane & 15)] =
                        (bf16)(accO[mf][nf][rr] * inv);
            }
    }
}

// ---------------------------------------------------------------------------
extern "C" void kernel_launch(void* const* d_in, const int* in_sizes, int n_in,
                              void* d_out, int out_size, void* d_ws, size_t ws_size,
                              hipStream_t stream)
{
    const float* queries = (const float*)d_in[0];
    const float* keys    = (const float*)d_in[1];
    const float* values  = (const float*)d_in[2];
    // d_in[3] = masks: statically causal, unused
    const float* Wq = (const float*)d_in[4];
    const float* Wk = (const float*)d_in[5];
    const float* Wv = (const float*)d_in[6];
    const float* Wo = (const float*)d_in[7];
    const float* bo = (const float*)d_in[8];
    float* out = (float*)d_out;

    bf16* Xq  = (bf16*)d_ws;          // 8192*1024
    bf16* Xk  = Xq  + 8388608;
    bf16* Xv  = Xk  + 8388608;
    bf16* WqT = Xv  + 8388608;        // 1024*1024 each
    bf16* WkT = WqT + 1048576;
    bf16* WvT = WkT + 1048576;
    bf16* WoT = WvT + 1048576;
    bf16* qp  = WoT + 1048576;        // [4][16][2048][64]
    bf16* kp  = qp  + 8388608;
    bf16* vTp = Xq;                   // [4][16][64][2048]  (alias, Xq dead after q-proj)
    bf16* ao  = Xk;                   // [8192][1024]       (alias, Xk dead after k-proj)
    if (ws_size < (size_t)92274688) return;

    cast3<<<dim3(2048), dim3(256), 0, stream>>>((const float4*)queries, (const float4*)keys,
                                                (const float4*)values,
                                                (bf16x4*)Xq, (bf16x4*)Xk, (bf16x4*)Xv);
    transw<<<dim3(16, 16), dim3(256), 0, stream>>>(Wq, Wk, Wv, Wo, WqT, WkT, WvT, WoT);
    gemm_qkv<<<dim3(512, 3), dim3(256), 0, stream>>>(Xq, WqT, qp, Xk, WkT, kp, WvT, Xv, vTp);
    attn<<<dim3(512), dim3(256), 0, stream>>>(qp, kp, vTp, ao);
    gemm_out<<<dim3(64, 8), dim3(256), 0, stream>>>(ao, WoT, out, bo);
}

// Round 10
// 406.946 us; speedup vs baseline: 1.1508x; 1.0821x over previous
//
#include <hip/hip_runtime.h>

// ---------------------------------------------------------------------------
// MultiHeadAttention: B=4 S=2048 MODEL=1024 H=16 Dk=Dv=64, causal.
// cast(QKV->bf16) ; LDS-tiled weight transpose (Wq pre-scaled 1/8) ;
// FUSED qkv proj GEMM ; flash causal attn (paired strips, XCD-chunked KV,
// SWAPPED QK^T -> lane-local softmax rows, defer-max, ones-MFMA row-sum) ;
// out GEMM (+bias, f32).
// Mask input is statically causal -> arithmetic.
// LDS tiles: 128B rows, XOR swizzle byte^=((row&7)<<4), global_load_lds(16B)
// from pre-swizzled global addresses (rule #21).
// ---------------------------------------------------------------------------

typedef __bf16 bf16;
typedef __attribute__((ext_vector_type(8))) __bf16 bf16x8;
typedef __attribute__((ext_vector_type(4))) __bf16 bf16x4;
typedef __attribute__((ext_vector_type(4))) float f32x4;
typedef unsigned int u32;

#define GLB_AS __attribute__((address_space(1)))
#define LDS_AS __attribute__((address_space(3)))

#define L2E 1.44269504088896340736f

static __device__ __forceinline__ void stage_swz(const bf16* __restrict__ g, long ldelem,
                                                 long row0, long col0,
                                                 bf16* lds, int rows, int tid)
{
    const int lane = tid & 63;
    const int wave = tid >> 6;
    const int nch = rows >> 3;                       // 1KB chunks
    for (int c = wave; c < nch; c += 4) {
        unsigned o  = ((unsigned)c << 10) + ((unsigned)lane << 4); // linear byte in tile
        unsigned r  = o >> 7;                         // tile row (128B/row)
        unsigned cb = o & 127u;                       // byte within row
        unsigned cs = cb ^ ((r & 7u) << 4);           // pre-swizzled source byte
        const bf16* src = g + (row0 + (long)r) * ldelem + col0 + (long)(cs >> 1);
        char* dst = (char*)lds + ((unsigned)c << 10); // wave-uniform, linear
        __builtin_amdgcn_global_load_lds((GLB_AS u32*)src, (LDS_AS u32*)dst, 16, 0, 0);
    }
}

// ---------------------------------------------------------------------------
// Prep kernels
// ---------------------------------------------------------------------------
__global__ void cast3(const float4* __restrict__ a, const float4* __restrict__ b,
                      const float4* __restrict__ c,
                      bf16x4* __restrict__ xa, bf16x4* __restrict__ xb,
                      bf16x4* __restrict__ xc)
{
    const int n4 = (8192 * 1024) / 4;
    for (int i = blockIdx.x * blockDim.x + threadIdx.x; i < n4; i += gridDim.x * blockDim.x) {
        float4 v;
        v = a[i]; xa[i] = (bf16x4){(bf16)v.x, (bf16)v.y, (bf16)v.z, (bf16)v.w};
        v = b[i]; xb[i] = (bf16x4){(bf16)v.x, (bf16)v.y, (bf16)v.z, (bf16)v.w};
        v = c[i]; xc[i] = (bf16x4){(bf16)v.x, (bf16)v.y, (bf16)v.z, (bf16)v.w};
    }
}

// LDS-tiled transposes (coalesced reads AND writes).
// Head weights [16][1024][64] -> WT[(h*64+d)][1024]; Wo [1024][1024] -> WoT[n][f].
__global__ void transw(const float* __restrict__ wq, const float* __restrict__ wk,
                       const float* __restrict__ wv, const float* __restrict__ wo,
                       bf16* __restrict__ wqT, bf16* __restrict__ wkT,
                       bf16* __restrict__ wvT, bf16* __restrict__ woT)
{
    __shared__ float t[64][65];
    const int tid = threadIdx.x, bx = blockIdx.x, by = blockIdx.y;
    const float* srcs[3] = {wq, wk, wv};
    bf16* dsts[3] = {wqT, wkT, wvT};
#pragma unroll
    for (int m = 0; m < 3; ++m) {
        const float sc = (m == 0) ? 0.125f : 1.0f;   // fold 1/sqrt(KEY) into Wq
        for (int i = tid; i < 4096; i += 256) {
            int r = i >> 6, c = i & 63;              // r: m-sub, c: d
            t[c][r] = srcs[m][by * 65536 + (bx * 64 + r) * 64 + c];
        }
        __syncthreads();
        for (int i = tid; i < 4096; i += 256) {
            int r = i >> 6, c = i & 63;              // r: d, c: m-sub
            dsts[m][(long)(by * 64 + r) * 1024 + bx * 64 + c] = (bf16)(t[r][c] * sc);
        }
        __syncthreads();
    }
    for (int i = tid; i < 4096; i += 256) {          // Wo: f=bx*64+r rows, n=by*64+c
        int r = i >> 6, c = i & 63;
        t[c][r] = wo[(long)(bx * 64 + r) * 1024 + by * 64 + c];
    }
    __syncthreads();
    for (int i = tid; i < 4096; i += 256) {
        int r = i >> 6, c = i & 63;
        woT[(long)(by * 64 + r) * 1024 + bx * 64 + c] = (bf16)t[r][c];
    }
}

// ---------------------------------------------------------------------------
// GEMM body: C[M][N] tile (128x128) = A[row0..][1024] * Bt[col0..][1024]^T.
// Single-buffered (32KB LDS) m97-style 2-barrier loop.
// MODE 0: bf16 out [b][h][s][64] ; MODE 2: f32 out + bias, row-major ;
// MODE 3: bf16 out vT [b][h][64][s] (row=hd, col=bs; s-contiguous).
// ---------------------------------------------------------------------------
template<int MODE>
static __device__ __forceinline__ void gemm_body(const bf16* __restrict__ A,
                                                 const bf16* __restrict__ Bt,
                                                 bf16* __restrict__ Cb,
                                                 float* __restrict__ Cf,
                                                 const float* __restrict__ bias,
                                                 long row0, long col0,
                                                 bf16* sA, bf16* sB)
{
    const int tid = threadIdx.x, lane = tid & 63, wave = tid >> 6;
    const int wr = wave >> 1, wc = wave & 1;

    f32x4 acc[4][4];
#pragma unroll
    for (int i = 0; i < 4; ++i)
#pragma unroll
        for (int j = 0; j < 4; ++j) acc[i][j] = (f32x4){0.f, 0.f, 0.f, 0.f};

    for (int kt = 0; kt < 16; ++kt) {
        __syncthreads();                             // prev-iter readers done
        stage_swz(A,  1024, row0, (long)kt << 6, sA, 128, tid);
        stage_swz(Bt, 1024, col0, (long)kt << 6, sB, 128, tid);
        __syncthreads();                             // vmcnt drain -> tiles ready
#pragma unroll
        for (int kk = 0; kk < 2; ++kk) {
            bf16x8 af[4], bfr[4];
            const unsigned kb = (unsigned)(kk << 6) + (unsigned)((lane >> 4) << 4);
#pragma unroll
            for (int i = 0; i < 4; ++i) {
                unsigned r = (unsigned)((wr << 6) + (i << 4) + (lane & 15));
                af[i] = *(const bf16x8*)((const char*)sA + (r << 7) + (kb ^ ((r & 7u) << 4)));
            }
#pragma unroll
            for (int j = 0; j < 4; ++j) {
                unsigned r = (unsigned)((wc << 6) + (j << 4) + (lane & 15));
                bfr[j] = *(const bf16x8*)((const char*)sB + (r << 7) + (kb ^ ((r & 7u) << 4)));
            }
#pragma unroll
            for (int i = 0; i < 4; ++i)
#pragma unroll
                for (int j = 0; j < 4; ++j)
                    acc[i][j] = __builtin_amdgcn_mfma_f32_16x16x32_bf16(af[i], bfr[j], acc[i][j], 0, 0, 0);
        }
    }

#pragma unroll
    for (int i = 0; i < 4; ++i) {
#pragma unroll
        for (int j = 0; j < 4; ++j) {
#pragma unroll
            for (int rr = 0; rr < 4; ++rr) {
                long row = row0 + (wr << 6) + (i << 4) + ((lane >> 4) << 2) + rr;
                long col = col0 + (wc << 6) + (j << 4) + (lane & 15);
                float v = acc[i][j][rr];
                if constexpr (MODE == 2) {
                    Cf[row * 1024 + col] = v + bias[col];
                } else if constexpr (MODE == 0) {
                    // row = b*2048+s, col = h*64+d
                    long idx = (((row >> 11) << 4) + (col >> 6)) * 131072 + (row & 2047) * 64 + (col & 63);
                    Cb[idx] = (bf16)v;
                } else {
                    // MODE 3: row = h*64+d, col = b*2048+s
                    long idx = ((((col >> 11) << 4) + (row >> 6)) * 64 + (row & 63)) * 2048 + (col & 2047);
                    Cb[idx] = (bf16)v;
                }
            }
        }
    }
}

// Fused q/k/v projections: grid (512, 3). op 0: q, op 1: k, op 2: v^T swapped.
__global__ __launch_bounds__(256, 3) void gemm_qkv(const bf16* __restrict__ Xq, const bf16* __restrict__ WqT, bf16* __restrict__ qp,
                                                   const bf16* __restrict__ Xk, const bf16* __restrict__ WkT, bf16* __restrict__ kp,
                                                   const bf16* __restrict__ WvT, const bf16* __restrict__ Xv, bf16* __restrict__ vTp)
{
    __shared__ alignas(16) bf16 sA[128 * 64];
    __shared__ alignas(16) bf16 sB[128 * 64];
    const int bx = blockIdx.x;
    if (blockIdx.y == 0)
        gemm_body<0>(Xq, WqT, qp, nullptr, nullptr, (long)(bx >> 3) << 7, (long)(bx & 7) << 7, sA, sB);
    else if (blockIdx.y == 1)
        gemm_body<0>(Xk, WkT, kp, nullptr, nullptr, (long)(bx >> 3) << 7, (long)(bx & 7) << 7, sA, sB);
    else
        gemm_body<3>(WvT, Xv, vTp, nullptr, nullptr, (long)(bx & 7) << 7, (long)(bx >> 3) << 7, sA, sB);
}

// Output projection (+bias, f32): grid (64, 8).
__global__ __launch_bounds__(256, 3) void gemm_out(const bf16* __restrict__ A, const bf16* __restrict__ Bt,
                                                   float* __restrict__ Cf, const float* __restrict__ bias)
{
    __shared__ alignas(16) bf16 sA[128 * 64];
    __shared__ alignas(16) bf16 sB[128 * 64];
    gemm_body<2>(A, Bt, nullptr, Cf, bias, (long)blockIdx.x << 7, (long)blockIdx.y << 7, sA, sB);
}

// ---------------------------------------------------------------------------
// Flash causal attention, paired strips + XCD-chunked KV + SWAPPED QK^T.
// Grid 512, 4 waves. hb=xcd*8+(idx&7); pair -> strips qt=pair / 15-pair
// (every block exactly 34 KV tiles). KV double-buffered.
// QK^T computed as S^T = mfma(K, Q): lane owns q = qw+mf*16+(lane&15) with
// 16 k-values in regs -> row-max = 15 fmax + 2 shfl (vs 32 shfl before);
// P-store = 8x ds_write_b64 (contiguous k per lane). Defer-max (THR=8):
// accO rescale (cf broadcast via 8 shfl, since accO's q-map differs) only on
// rare max-growth events. Row-sum l via ones-MFMA. Wq pre-scaled by 1/8.
// ---------------------------------------------------------------------------
__global__ __launch_bounds__(256, 2) void attn(const bf16* __restrict__ q,
                                               const bf16* __restrict__ k,
                                               const bf16* __restrict__ vT,
                                               bf16* __restrict__ o)
{
    __shared__ alignas(16) bf16 sK[2][64 * 64];
    __shared__ alignas(16) bf16 sV[2][64 * 64];
    __shared__ alignas(16) bf16 sP[4][32 * 72];     // per-wave [q][k], stride 72
    const int tid = threadIdx.x, lane = tid & 63, wave = tid >> 6;
    const int bid = blockIdx.x;
    const int hb = ((bid & 7) << 3) + ((bid >> 3) & 7);
    const int pair = bid >> 6;                      // 0..7
    const int h = hb & 15, b = hb >> 4;
    const bf16* qh = q  + (long)hb * 131072;        // [2048][64]
    const bf16* kh = k  + (long)hb * 131072;        // [2048][64]
    const bf16* vh = vT + (long)hb * 131072;        // [64][2048]

    bf16x8 vone;
#pragma unroll
    for (int i = 0; i < 8; ++i) vone[i] = (bf16)1.0f;

    for (int half = 0; half < 2; ++half) {
        const int qt = half ? (15 - pair) : pair;
        const int qw = (qt << 7) + (wave << 5);     // wave's first q row

        bf16x8 aq[2][2];                            // Q fragments (B-operand)
#pragma unroll
        for (int mf = 0; mf < 2; ++mf)
#pragma unroll
            for (int kk = 0; kk < 2; ++kk)
                aq[mf][kk] = *(const bf16x8*)(qh + (long)(qw + (mf << 4) + (lane & 15)) * 64
                                                 + (kk << 5) + ((lane >> 4) << 3));

        f32x4 accO[2][4], accOl[2];
        float mrow[2];                              // per-lane q = qw+mf*16+(lane&15)
#pragma unroll
        for (int mf = 0; mf < 2; ++mf) {
#pragma unroll
            for (int nf = 0; nf < 4; ++nf) accO[mf][nf] = (f32x4){0.f, 0.f, 0.f, 0.f};
            accOl[mf] = (f32x4){0.f, 0.f, 0.f, 0.f};
            mrow[mf] = -1e30f;
        }

        const int nkv = (qt << 1) + 2;
        __syncthreads();                            // prev strip's readers done
        stage_swz(kh, 64,   0, 0, sK[0], 64, tid);
        stage_swz(vh, 2048, 0, 0, sV[0], 64, tid);

        for (int kvt = 0; kvt < nkv; ++kvt) {
            const int cur = kvt & 1;
            const int kv0 = kvt << 6;
            __syncthreads();                        // vmcnt drain -> sK/sV[cur] ready
            if (kvt + 1 < nkv) {                    // prefetch next into [cur^1]
                stage_swz(kh, 64,   (long)(kv0 + 64), 0, sK[cur ^ 1], 64, tid);
                stage_swz(vh, 2048, 0, (long)(kv0 + 64), sV[cur ^ 1], 64, tid);
            }
            if (kv0 > qw + 31) continue;            // fully masked for this wave

            // S^T = mfma(K, Q): lane holds q=(lane&15)+16mf, k=(lane>>4)*4+reg+16nf
            f32x4 s[2][4];
#pragma unroll
            for (int mf = 0; mf < 2; ++mf)
#pragma unroll
                for (int nf = 0; nf < 4; ++nf) s[mf][nf] = (f32x4){0.f, 0.f, 0.f, 0.f};
#pragma unroll
            for (int kk = 0; kk < 2; ++kk) {
                bf16x8 bk[4];                       // K fragments (A-operand)
                const unsigned kb = (unsigned)(kk << 6) + (unsigned)((lane >> 4) << 4);
#pragma unroll
                for (int nf = 0; nf < 4; ++nf) {
                    unsigned r = (unsigned)((nf << 4) + (lane & 15));
                    bk[nf] = *(const bf16x8*)((const char*)sK[cur] + (r << 7) + (kb ^ ((r & 7u) << 4)));
                }
#pragma unroll
                for (int mf = 0; mf < 2; ++mf)
#pragma unroll
                    for (int nf = 0; nf < 4; ++nf)
                        s[mf][nf] = __builtin_amdgcn_mfma_f32_16x16x32_bf16(bk[nf], aq[mf][kk], s[mf][nf], 0, 0, 0);
            }

            const int g4 = (lane >> 4) << 2;

            // causal mask (diagonal tiles only): k = kv0+nf*16+g4+reg, q lane-local
            if (kv0 + 63 > qw) {
#pragma unroll
                for (int mf = 0; mf < 2; ++mf) {
                    const int qv = qw + (mf << 4) + (lane & 15);
#pragma unroll
                    for (int nf = 0; nf < 4; ++nf)
#pragma unroll
                        for (int reg = 0; reg < 4; ++reg)
                            if (kv0 + (nf << 4) + g4 + reg > qv) s[mf][nf][reg] = -1e30f;
                }
            }

            // lane-local softmax: 15 fmax + 2 shfl per mf; defer-max THR=8
            bool upAny = false;
            float cfl[2];
#pragma unroll
            for (int mf = 0; mf < 2; ++mf) {
                float m0 = fmaxf(fmaxf(s[mf][0][0], s[mf][0][1]), fmaxf(s[mf][0][2], s[mf][0][3]));
                float m1 = fmaxf(fmaxf(s[mf][1][0], s[mf][1][1]), fmaxf(s[mf][1][2], s[mf][1][3]));
                float m2_ = fmaxf(fmaxf(s[mf][2][0], s[mf][2][1]), fmaxf(s[mf][2][2], s[mf][2][3]));
                float m3 = fmaxf(fmaxf(s[mf][3][0], s[mf][3][1]), fmaxf(s[mf][3][2], s[mf][3][3]));
                float mt = fmaxf(fmaxf(m0, m1), fmaxf(m2_, m3));
                mt = fmaxf(mt, __shfl_xor(mt, 16));
                mt = fmaxf(mt, __shfl_xor(mt, 32));
                const bool up = mt > mrow[mf] + 8.0f;
                cfl[mf] = up ? __builtin_exp2f((mrow[mf] - mt) * L2E) : 1.0f;
                if (up) mrow[mf] = mt;
                upAny = upAny || up;
                const float mm = mrow[mf] * L2E;
#pragma unroll
                for (int nf = 0; nf < 4; ++nf)
#pragma unroll
                    for (int reg = 0; reg < 4; ++reg)
                        s[mf][nf][reg] = __builtin_exp2f(__builtin_fmaf(s[mf][nf][reg], L2E, -mm));
            }
            if (__any(upAny)) {                     // rare: broadcast cf to accO's q-map
#pragma unroll
                for (int mf = 0; mf < 2; ++mf)
#pragma unroll
                    for (int reg = 0; reg < 4; ++reg) {
                        const float c = __shfl(cfl[mf], g4 + reg);
                        accOl[mf][reg] *= c;
#pragma unroll
                        for (int nf = 0; nf < 4; ++nf) accO[mf][nf][reg] *= c;
                    }
            }

            // P -> per-wave LDS [q][k]: 8x ds_write_b64 (contiguous k per lane)
            bf16* pw = &sP[wave][0];
#pragma unroll
            for (int mf = 0; mf < 2; ++mf) {
                bf16* pp = pw + ((mf << 4) + (lane & 15)) * 72 + g4;
#pragma unroll
                for (int nf = 0; nf < 4; ++nf) {
                    bf16x4 pv = {(bf16)s[mf][nf][0], (bf16)s[mf][nf][1],
                                 (bf16)s[mf][nf][2], (bf16)s[mf][nf][3]};
                    *(bf16x4*)(pp + (nf << 4)) = pv;
                }
            }

#pragma unroll
            for (int kk = 0; kk < 2; ++kk) {
                bf16x8 pa[2], bv[4];
#pragma unroll
                for (int mf = 0; mf < 2; ++mf)
                    pa[mf] = *(const bf16x8*)(pw + (((mf << 4) + (lane & 15)) * 72)
                                                 + (kk << 5) + ((lane >> 4) << 3));
                const unsigned kb = (unsigned)(kk << 6) + (unsigned)((lane >> 4) << 4);
#pragma unroll
                for (int nf = 0; nf < 4; ++nf) {
                    unsigned r = (unsigned)((nf << 4) + (lane & 15));
                    bv[nf] = *(const bf16x8*)((const char*)sV[cur] + (r << 7) + (kb ^ ((r & 7u) << 4)));
                }
#pragma unroll
                for (int mf = 0; mf < 2; ++mf) {
#pragma unroll
                    for (int nf = 0; nf < 4; ++nf)
                        accO[mf][nf] = __builtin_amdgcn_mfma_f32_16x16x32_bf16(pa[mf], bv[nf], accO[mf][nf], 0, 0, 0);
                    accOl[mf] = __builtin_amdgcn_mfma_f32_16x16x32_bf16(pa[mf], vone, accOl[mf], 0, 0, 0);
                }
            }
        }

        // O /= l ; write [b][s][h*64+d] bf16  (accO: q=qw+mf*16+g4+rr, d=nf*16+lane&15)
#pragma unroll
        for (int mf = 0; mf < 2; ++mf)
#pragma unroll
            for (int rr = 0; rr < 4; ++rr) {
                const float inv = 1.f / accOl[mf][rr];
                const long ra = qw + (mf << 4) + ((lane >> 4) << 2) + rr;
#pragma unroll
                for (int nf = 0; nf < 4; ++nf)
                    o[((long)b * 2048 + ra) * 1024 + (h << 6) + (nf << 4) + (lane & 15)] =
                        (bf16)(accO[mf][nf][rr] * inv);
            }
    }
}

// ---------------------------------------------------------------------------
extern "C" void kernel_launch(void* const* d_in, const int* in_sizes, int n_in,
                              void* d_out, int out_size, void* d_ws, size_t ws_size,
                              hipStream_t stream)
{
    const float* queries = (const float*)d_in[0];
    const float* keys    = (const float*)d_in[1];
    const float* values  = (const float*)d_in[2];
    // d_in[3] = masks: statically causal, unused
    const float* Wq = (const float*)d_in[4];
    const float* Wk = (const float*)d_in[5];
    const float* Wv = (const float*)d_in[6];
    const float* Wo = (const float*)d_in[7];
    const float* bo = (const float*)d_in[8];
    float* out = (float*)d_out;

    bf16* Xq  = (bf16*)d_ws;          // 8192*1024
    bf16* Xk  = Xq  + 8388608;
    bf16* Xv  = Xk  + 8388608;
    bf16* WqT = Xv  + 8388608;        // 1024*1024 each
    bf16* WkT = WqT + 1048576;
    bf16* WvT = WkT + 1048576;
    bf16* WoT = WvT + 1048576;
    bf16* qp  = WoT + 1048576;        // [4][16][2048][64]
    bf16* kp  = qp  + 8388608;
    bf16* vTp = Xq;                   // [4][16][64][2048]  (alias, Xq dead after q-proj)
    bf16* ao  = Xk;                   // [8192][1024]       (alias, Xk dead after k-proj)
    if (ws_size < (size_t)92274688) return;

    cast3<<<dim3(2048), dim3(256), 0, stream>>>((const float4*)queries, (const float4*)keys,
                                                (const float4*)values,
                                                (bf16x4*)Xq, (bf16x4*)Xk, (bf16x4*)Xv);
    transw<<<dim3(16, 16), dim3(256), 0, stream>>>(Wq, Wk, Wv, Wo, WqT, WkT, WvT, WoT);
    gemm_qkv<<<dim3(512, 3), dim3(256), 0, stream>>>(Xq, WqT, qp, Xk, WkT, kp, WvT, Xv, vTp);
    attn<<<dim3(512), dim3(256), 0, stream>>>(qp, kp, vTp, ao);
    gemm_out<<<dim3(64, 8), dim3(256), 0, stream>>>(ao, WoT, out, bo);
}